// Round 7
// baseline (583.132 us; speedup 1.0000x reference)
//
#include <hip/hip_runtime.h>

// VectorQuantizer: inputs [8,4096,64] f32, weight [8192,64] f32.
// Outputs concat: quantized_st [2097152] f32, loss [1] f32, indices [32768] f32.
//
// R7: 3 dispatches. Identical to R6 except vq_finish P2 reads xs[] from LDS
// (R6's xr[64] per-thread array spilled to scratch at VGPR=56 -> 412us of
// latency stalls + 31ms first-touch outlier).
//  - vq_prep:   wsq/wsqC (np-exact), packedW bf16-split B-fragments, loss=0.
//  - vq_argmin: barrier-free MFMA top-2, 10-bit (tile,col) id embedded in the
//               packed uint key -> pure umin/umax butterfly reduction.
//  - vq_finish: fused merge + np-exact rescan of near-ties (MARGIN 1.5e-3
//               covers 3-term GEMM err 7e-5 + 1024-ulp key truncation ~5e-4)
//               + gather/STE/loss/index epilogue.

typedef short bf16x8 __attribute__((ext_vector_type(8)));
typedef float f32x4  __attribute__((ext_vector_type(4)));

#define N_ROWS 32768
#define DIM 64
#define K_CODES 8192
#define KSPLIT 8
#define KCHUNK 1024
#define OUT_Q 0
#define OUT_LOSS 2097152
#define OUT_IDX 2097153
#define MARGIN 1.5e-3f
#define C_OFF 4.0f     // c' = c + 4 > 0 always (empirically held R4-R6)

// ---- helpers ----
__device__ __forceinline__ unsigned f2u_ord(float f) {
    unsigned u = __float_as_uint(f);
    return (u & 0x80000000u) ? ~u : (u | 0x80000000u);
}
__device__ __forceinline__ float u2f_ord(unsigned u) {
    unsigned v = (u & 0x80000000u) ? (u & 0x7fffffffu) : ~u;
    return __uint_as_float(v);
}
__device__ __forceinline__ unsigned short bf16_rne(float f) {
    unsigned u = __float_as_uint(f);
    u += 0x7fffu + ((u >> 16) & 1u);
    return (unsigned short)(u >> 16);
}
__device__ __forceinline__ float bf16_to_f(unsigned short h) {
    return __uint_as_float(((unsigned)h) << 16);
}

// numpy pairwise_sum over 64 squared elements (exact np emulation)
__device__ __forceinline__ float np_pairwise_sq64(const float* v) {
    float r[8];
#pragma unroll
    for (int j = 0; j < 8; j++) r[j] = __fmul_rn(v[j], v[j]);
#pragma unroll
    for (int i = 8; i < 64; i += 8) {
#pragma unroll
        for (int j = 0; j < 8; j++)
            r[j] = __fadd_rn(r[j], __fmul_rn(v[i + j], v[i + j]));
    }
    return __fadd_rn(__fadd_rn(__fadd_rn(r[0], r[1]), __fadd_rn(r[2], r[3])),
                     __fadd_rn(__fadd_rn(r[4], r[5]), __fadd_rn(r[6], r[7])));
}

// ---------------- kernel 0: fused prep -------------------------------------
__global__ __launch_bounds__(256) void vq_prep(const float* __restrict__ weight,
                                               float* __restrict__ wsq,
                                               float* __restrict__ wsqC,
                                               int4* __restrict__ packedW,
                                               float* __restrict__ out) {
    __shared__ float sW[64 * 65];
    int tid = threadIdx.x;
    int cbase = blockIdx.x * 64;

    const float4* gw = (const float4*)(weight + (size_t)cbase * DIM);
#pragma unroll
    for (int i = 0; i < 4; i++) {
        int e = i * 256 + tid;
        float4 v = gw[e];
        int code = e >> 4, d4 = e & 15;
        float* dst = &sW[code * 65 + d4 * 4];
        dst[0] = v.x; dst[1] = v.y; dst[2] = v.z; dst[3] = v.w;
    }
    __syncthreads();

    if (tid < 64) {
        float s = np_pairwise_sq64(&sW[tid * 65]);
        wsq [cbase + tid] = s;
        wsqC[cbase + tid] = s + C_OFF;
    }
    if (blockIdx.x == 0 && tid == 0) out[OUT_LOSS] = 0.f;

    int wave = tid >> 6, lane = tid & 63;
    int tile = blockIdx.x * 4 + wave;
    int codeL = wave * 16 + (lane & 15);
    int kq = (lane >> 4) * 8;
    const float* wp = &sW[codeL * 65];

    union { bf16x8 v; int4 q; } hi0, hi1, lo0, lo1;
#pragma unroll
    for (int j = 0; j < 8; j++) {
        float a = wp[kq + j];
        unsigned short ha = bf16_rne(a);
        hi0.v[j] = (short)ha;
        lo0.v[j] = (short)bf16_rne(a - bf16_to_f(ha));
        float b = wp[32 + kq + j];
        unsigned short hb = bf16_rne(b);
        hi1.v[j] = (short)hb;
        lo1.v[j] = (short)bf16_rne(b - bf16_to_f(hb));
    }
    size_t base = (size_t)tile * 4 * 64;
    packedW[base + 0 * 64 + lane] = hi0.q;
    packedW[base + 1 * 64 + lane] = hi1.q;
    packedW[base + 2 * 64 + lane] = lo0.q;
    packedW[base + 3 * 64 + lane] = lo1.q;
}

// ---------------- kernel 1: barrier-free MFMA argmin top-2 ------------------
__global__ __launch_bounds__(256) void vq_argmin(const float* __restrict__ inp,
                                                 const int4* __restrict__ packedW,
                                                 const float* __restrict__ wsqC,
                                                 unsigned long long* __restrict__ bestk,
                                                 float* __restrict__ secd) {
    int wave = threadIdx.x >> 6;
    int lane = threadIdx.x & 63;
    int col  = lane & 15;
    int rbase = blockIdx.x * 128 + wave * 32;
    int kbase = blockIdx.y * KCHUNK;

    // A fragments: lane holds A[m=lane&15][k=(lane>>4)*8+j]
    int kq = (lane >> 4) * 8;
    bf16x8 ah[2][2], al[2][2];
#pragma unroll
    for (int rt = 0; rt < 2; rt++) {
        const float* xp = inp + (size_t)(rbase + rt * 16 + col) * DIM;
#pragma unroll
        for (int kc = 0; kc < 2; kc++) {
            const float4* xq = (const float4*)(xp + kc * 32 + kq);
            float4 a0 = xq[0], a1 = xq[1];
            float xe[8] = {a0.x, a0.y, a0.z, a0.w, a1.x, a1.y, a1.z, a1.w};
#pragma unroll
            for (int j = 0; j < 8; j++) {
                unsigned short h = bf16_rne(xe[j]);
                ah[rt][kc][j] = (short)h;
                al[rt][kc][j] = (short)bf16_rne(xe[j] - bf16_to_f(h));
            }
        }
    }

    unsigned best_u[8], sec_u[8];
#pragma unroll
    for (int s = 0; s < 8; s++) { best_u[s] = 0xFFFFFFFFu; sec_u[s] = 0xFFFFFFFFu; }

    const char* wb = (const char*)packedW + (size_t)kbase * 256;
    const float* wq = wsqC + kbase + col;

    for (int g = 0; g < 16; g++) {
#pragma unroll
        for (int t = 0; t < 4; t++) {
            const int4* p = (const int4*)(wb + (size_t)(g * 4 + t) * 4096);
            union { int4 q; bf16x8 v; } bh0, bh1, bl0, bl1;
            bh0.q = p[0 * 64 + lane];
            bh1.q = p[1 * 64 + lane];
            bl0.q = p[2 * 64 + lane];
            bl1.q = p[3 * 64 + lane];
            float wsqv = wq[g * 64 + t * 16];
            // key low-10 bits = (tile_id<<4) | col  => code - kbase
            unsigned sxor = (1023u ^ (unsigned)((g * 4 + t) << 4)) ^ (unsigned)col;
#pragma unroll
            for (int rt = 0; rt < 2; rt++) {
                f32x4 acc = {0.f, 0.f, 0.f, 0.f};
                acc = __builtin_amdgcn_mfma_f32_16x16x32_bf16(ah[rt][0], bh0.v, acc, 0, 0, 0);
                acc = __builtin_amdgcn_mfma_f32_16x16x32_bf16(ah[rt][1], bh1.v, acc, 0, 0, 0);
                acc = __builtin_amdgcn_mfma_f32_16x16x32_bf16(al[rt][0], bh0.v, acc, 0, 0, 0);
                acc = __builtin_amdgcn_mfma_f32_16x16x32_bf16(al[rt][1], bh1.v, acc, 0, 0, 0);
                acc = __builtin_amdgcn_mfma_f32_16x16x32_bf16(ah[rt][0], bl0.v, acc, 0, 0, 0);
                acc = __builtin_amdgcn_mfma_f32_16x16x32_bf16(ah[rt][1], bl1.v, acc, 0, 0, 0);
#pragma unroll
                for (int r = 0; r < 4; r++) {
                    float c = fmaf(-2.0f, acc[r], wsqv);            // c' = c + 4 > 0
                    unsigned k = (__float_as_uint(c) | 1023u) ^ sxor;
                    int s = rt * 4 + r;
                    unsigned mx = (best_u[s] > k) ? best_u[s] : k;
                    sec_u[s]  = (sec_u[s] < mx) ? sec_u[s] : mx;
                    best_u[s] = (best_u[s] < k) ? best_u[s] : k;
                }
            }
        }
    }

    // pure-uint butterfly across the 16 columns (id rides in the low 10 bits)
#pragma unroll
    for (int m = 1; m < 16; m <<= 1) {
#pragma unroll
        for (int s = 0; s < 8; s++) {
            unsigned ob = (unsigned)__shfl_xor((int)best_u[s], m, 64);
            unsigned os = (unsigned)__shfl_xor((int)sec_u[s], m, 64);
            unsigned mx = (best_u[s] > ob) ? best_u[s] : ob;
            unsigned sm = (sec_u[s] < os) ? sec_u[s] : os;
            sec_u[s]  = (sm < mx) ? sm : mx;
            best_u[s] = (best_u[s] < ob) ? best_u[s] : ob;
        }
    }
    if (col == 0) {
        int g4 = lane >> 4;
#pragma unroll
        for (int rt = 0; rt < 2; rt++)
#pragma unroll
            for (int r = 0; r < 4; r++) {
                int row = rbase + rt * 16 + g4 * 4 + r;
                int s = rt * 4 + r;
                unsigned bk = best_u[s], sk = sec_u[s];
                int code = kbase + (int)(bk & 1023u);
                float cb = __uint_as_float(bk | 1023u) - C_OFF;
                float cs = __uint_as_float(sk | 1023u) - C_OFF;
                bestk[(size_t)blockIdx.y * N_ROWS + row] =
                    ((unsigned long long)f2u_ord(cb) << 32) | (unsigned)code;
                secd [(size_t)blockIdx.y * N_ROWS + row] = cs;
            }
    }
}

// ---------------- kernel 2: fused merge + np-exact rescan + epilogue --------
// 256 blocks x 256 threads; block owns 128 rows.
__global__ __launch_bounds__(256) void vq_finish(const float* __restrict__ inp,
                                                 const float* __restrict__ weight,
                                                 const float* __restrict__ wsq,
                                                 const unsigned long long* __restrict__ bestk,
                                                 const float* __restrict__ secd,
                                                 float* __restrict__ out) {
    __shared__ int   sIdx[128];
    __shared__ int   sFlag[128];
    __shared__ int   sCnt;
    __shared__ float xs[DIM];
    __shared__ float x2s;
    __shared__ float rd[256];
    __shared__ int   ri[256];
    __shared__ float lred[4];

    int tid = threadIdx.x;
    int rbase = blockIdx.x * 128;
    if (tid == 0) sCnt = 0;
    __syncthreads();

    // ---- P1: merge the KSPLIT chunk results ----
    if (tid < 128) {
        int row = rbase + tid;
        unsigned long long ks[KSPLIT];
#pragma unroll
        for (int c = 0; c < KSPLIT; c++) ks[c] = bestk[(size_t)c * N_ROWS + row];
        unsigned long long k1 = ks[0];
#pragma unroll
        for (int c = 1; c < KSPLIT; c++) k1 = (ks[c] < k1) ? ks[c] : k1;
        float d1 = u2f_ord((unsigned)(k1 >> 32));
        float d2 = 3.402823466e+38f;
#pragma unroll
        for (int c = 0; c < KSPLIT; c++) {
            if (ks[c] != k1) {
                float bd = u2f_ord((unsigned)(ks[c] >> 32));
                if (bd < d2) d2 = bd;
            }
            float sd = secd[(size_t)c * N_ROWS + row];
            if (sd < d2) d2 = sd;
        }
        sIdx[tid] = (int)(k1 & 0xffffffffull);
        if (d2 - d1 < MARGIN) {
            int sl = atomicAdd(&sCnt, 1);
            sFlag[sl] = tid;
        }
    }
    __syncthreads();

    // ---- P2: np-exact rescan of flagged rows (operands from LDS, no spill) --
    int cnt = sCnt;
    for (int li = 0; li < cnt; li++) {
        int lrow = sFlag[li];
        int row = rbase + lrow;
        if (tid < DIM) xs[tid] = inp[(size_t)row * DIM + tid];
        __syncthreads();
        if (tid == 0) x2s = np_pairwise_sq64(xs);
        __syncthreads();
        float x2 = x2s;

        float bd = 3.402823466e+38f;
        int bi = 0x7fffffff;
#pragma unroll 4
        for (int code = tid; code < K_CODES; code += 256) {
            const float* wp = weight + (size_t)code * DIM;
            float s = 0.f;
#pragma unroll
            for (int i = 0; i < DIM; i++) s = __builtin_fmaf(xs[i], wp[i], s);
            float t1 = __fadd_rn(x2, wsq[code]);
            float d  = __fsub_rn(t1, __fmul_rn(2.0f, s));
            if (d < bd) { bd = d; bi = code; }
        }
        rd[tid] = bd; ri[tid] = bi;
        __syncthreads();
        for (int st = 128; st > 0; st >>= 1) {
            if (tid < st) {
                if (rd[tid + st] < rd[tid] ||
                    (rd[tid + st] == rd[tid] && ri[tid + st] < ri[tid])) {
                    rd[tid] = rd[tid + st]; ri[tid] = ri[tid + st];
                }
            }
            __syncthreads();
        }
        if (tid == 0) sIdx[lrow] = ri[0];
        __syncthreads();
    }

    // ---- P3: gather + STE + loss + index write for this block's 128 rows ----
    float lp = 0.f;
    const float4* xin = (const float4*)inp;
    const float4* wf  = (const float4*)weight;
#pragma unroll
    for (int it = 0; it < 8; it++) {
        int e = it * 256 + tid;          // local float4 index, 0..2047
        int rl = e >> 4, sub = e & 15;
        int gid = rbase * 16 + e;
        int idx = sIdx[rl];
        float4 x = xin[gid];
        float4 w = wf[idx * 16 + sub];
        float4 q;
        q.x = x.x + (w.x - x.x);
        q.y = x.y + (w.y - x.y);
        q.z = x.z + (w.z - x.z);
        q.w = x.w + (w.w - x.w);
        ((float4*)(out + OUT_Q))[gid] = q;
        if (sub == 0) out[OUT_IDX + rbase + rl] = (float)idx;
        float dx = w.x - x.x, dy = w.y - x.y, dz = w.z - x.z, dw = w.w - x.w;
        lp += dx * dx + dy * dy + dz * dz + dw * dw;
    }
#pragma unroll
    for (int o = 32; o > 0; o >>= 1) lp += __shfl_down(lp, o, 64);
    int wid = tid >> 6, lane = tid & 63;
    if (lane == 0) lred[wid] = lp;
    __syncthreads();
    if (tid == 0) {
        float bs = lred[0] + lred[1] + lred[2] + lred[3];
        atomicAdd(out + OUT_LOSS, bs * (0.25f / 2097152.f));
    }
}

extern "C" void kernel_launch(void* const* d_in, const int* in_sizes, int n_in,
                              void* d_out, int out_size, void* d_ws, size_t ws_size,
                              hipStream_t stream) {
    const float* inp = (const float*)d_in[0];
    const float* weight = (const float*)d_in[1];
    float* out = (float*)d_out;

    char* ws = (char*)d_ws;
    unsigned long long* bestk = (unsigned long long*)ws;              // 2 MB
    float* secd      = (float*)(ws + (size_t)KSPLIT * N_ROWS * 8);    // 1 MB
    char*  p         = ws + (size_t)KSPLIT * N_ROWS * 12;
    float* wsq       = (float*)p;                                     // 32 KB
    float* wsqC      = (float*)(p + 32768);                           // 32 KB
    int4*  packedW   = (int4*)(p + 65536);                            // 2 MB

    vq_prep<<<128, 256, 0, stream>>>(weight, wsq, wsqC, packedW, out);
    vq_argmin<<<dim3(N_ROWS / 128, KSPLIT), 256, 0, stream>>>(inp, packedW, wsqC, bestk, secd);
    vq_finish<<<256, 256, 0, stream>>>(inp, weight, wsq, bestk, secd, out);
}

// Round 8
// 366.947 us; speedup vs baseline: 1.5891x; 1.5891x over previous
//
#include <hip/hip_runtime.h>

// VectorQuantizer: inputs [8,4096,64] f32, weight [8192,64] f32.
// Outputs concat: quantized_st [2097152] f32, loss [1] f32, indices [32768] f32.
//
// R8: 5 dispatches.
//  - vq_prep:    wsq/wsqC (np-exact), packedW hi-only bf16 B-fragments (1MB),
//                zero loss + flag counter.
//  - vq_argmin:  2-term bf16-split MFMA (xh*wh + xl*wh), barrier-free, 10-bit
//                id in packed uint key, pure umin/umax butterfly.
//  - vq_merge:   cross-chunk top-2 merge, final_idx + GLOBAL flag list
//                (MARGIN 5e-3 covers 2-term err ~6sigma + key truncation).
//  - vq_rescan:  load-balanced np-exact re-resolve, 4 rows/batch sharing
//                float4 weight reads (4 independent FMA chains).
//  - vq_epilogue: gather + STE + loss + index write.

typedef short bf16x8 __attribute__((ext_vector_type(8)));
typedef float f32x4  __attribute__((ext_vector_type(4)));

#define N_ROWS 32768
#define DIM 64
#define K_CODES 8192
#define KSPLIT 8
#define KCHUNK 1024
#define OUT_Q 0
#define OUT_LOSS 2097152
#define OUT_IDX 2097153
#define MARGIN 5e-3f
#define C_OFF 4.0f     // c' = c + 4 > 0 always (empirically held R4-R7)

// ---- helpers ----
__device__ __forceinline__ unsigned umn(unsigned a, unsigned b) { return a < b ? a : b; }
__device__ __forceinline__ unsigned umx(unsigned a, unsigned b) { return a > b ? a : b; }
__device__ __forceinline__ unsigned f2u_ord(float f) {
    unsigned u = __float_as_uint(f);
    return (u & 0x80000000u) ? ~u : (u | 0x80000000u);
}
__device__ __forceinline__ float u2f_ord(unsigned u) {
    unsigned v = (u & 0x80000000u) ? (u & 0x7fffffffu) : ~u;
    return __uint_as_float(v);
}
__device__ __forceinline__ unsigned short bf16_rne(float f) {
    unsigned u = __float_as_uint(f);
    u += 0x7fffu + ((u >> 16) & 1u);
    return (unsigned short)(u >> 16);
}
__device__ __forceinline__ float bf16_to_f(unsigned short h) {
    return __uint_as_float(((unsigned)h) << 16);
}

// numpy pairwise_sum over 64 squared elements (exact np emulation)
__device__ __forceinline__ float np_pairwise_sq64(const float* v) {
    float r[8];
#pragma unroll
    for (int j = 0; j < 8; j++) r[j] = __fmul_rn(v[j], v[j]);
#pragma unroll
    for (int i = 8; i < 64; i += 8) {
#pragma unroll
        for (int j = 0; j < 8; j++)
            r[j] = __fadd_rn(r[j], __fmul_rn(v[i + j], v[i + j]));
    }
    return __fadd_rn(__fadd_rn(__fadd_rn(r[0], r[1]), __fadd_rn(r[2], r[3])),
                     __fadd_rn(__fadd_rn(r[4], r[5]), __fadd_rn(r[6], r[7])));
}

// ---------------- kernel 0: prep -------------------------------------------
// packedW layout: [tile(512)][frag(2)][lane(64)] x int4; frag 0=hi_k0 1=hi_k32
// B-frag lane holds B[k=(lane>>4)*8+j][n=lane&15] as bf16x8.
__global__ __launch_bounds__(256) void vq_prep(const float* __restrict__ weight,
                                               float* __restrict__ wsq,
                                               float* __restrict__ wsqC,
                                               int4* __restrict__ packedW,
                                               int* __restrict__ rcount,
                                               float* __restrict__ out) {
    __shared__ float sW[64 * 65];
    int tid = threadIdx.x;
    int cbase = blockIdx.x * 64;

    const float4* gw = (const float4*)(weight + (size_t)cbase * DIM);
#pragma unroll
    for (int i = 0; i < 4; i++) {
        int e = i * 256 + tid;
        float4 v = gw[e];
        int code = e >> 4, d4 = e & 15;
        float* dst = &sW[code * 65 + d4 * 4];
        dst[0] = v.x; dst[1] = v.y; dst[2] = v.z; dst[3] = v.w;
    }
    __syncthreads();

    if (tid < 64) {
        float s = np_pairwise_sq64(&sW[tid * 65]);
        wsq [cbase + tid] = s;
        wsqC[cbase + tid] = s + C_OFF;
    }
    if (blockIdx.x == 0 && tid == 0) { out[OUT_LOSS] = 0.f; *rcount = 0; }

    int wave = tid >> 6, lane = tid & 63;
    int tile = blockIdx.x * 4 + wave;
    int codeL = wave * 16 + (lane & 15);
    int kq = (lane >> 4) * 8;
    const float* wp = &sW[codeL * 65];

    union { bf16x8 v; int4 q; } hi0, hi1;
#pragma unroll
    for (int j = 0; j < 8; j++) {
        hi0.v[j] = (short)bf16_rne(wp[kq + j]);
        hi1.v[j] = (short)bf16_rne(wp[32 + kq + j]);
    }
    size_t base = (size_t)tile * 2 * 64;
    packedW[base + lane]      = hi0.q;
    packedW[base + 64 + lane] = hi1.q;
}

// ---------------- kernel 1: barrier-free 2-term MFMA argmin top-2 -----------
__global__ __launch_bounds__(256) void vq_argmin(const float* __restrict__ inp,
                                                 const int4* __restrict__ packedW,
                                                 const float* __restrict__ wsqC,
                                                 unsigned long long* __restrict__ bestk,
                                                 float* __restrict__ secd) {
    int wave = threadIdx.x >> 6;
    int lane = threadIdx.x & 63;
    int col  = lane & 15;
    int rbase = blockIdx.x * 128 + wave * 32;
    int kbase = blockIdx.y * KCHUNK;

    // A fragments: lane holds A[m=lane&15][k=(lane>>4)*8+j]
    int kq = (lane >> 4) * 8;
    bf16x8 ah[2][2], al[2][2];
#pragma unroll
    for (int rt = 0; rt < 2; rt++) {
        const float* xp = inp + (size_t)(rbase + rt * 16 + col) * DIM;
#pragma unroll
        for (int kc = 0; kc < 2; kc++) {
            const float4* xq = (const float4*)(xp + kc * 32 + kq);
            float4 a0 = xq[0], a1 = xq[1];
            float xe[8] = {a0.x, a0.y, a0.z, a0.w, a1.x, a1.y, a1.z, a1.w};
#pragma unroll
            for (int j = 0; j < 8; j++) {
                unsigned short h = bf16_rne(xe[j]);
                ah[rt][kc][j] = (short)h;
                al[rt][kc][j] = (short)bf16_rne(xe[j] - bf16_to_f(h));
            }
        }
    }

    unsigned best_u[8], sec_u[8];
#pragma unroll
    for (int s = 0; s < 8; s++) { best_u[s] = 0xFFFFFFFFu; sec_u[s] = 0xFFFFFFFFu; }

    const char* wb = (const char*)packedW + (size_t)kbase * 128;   // (kbase/16)*2048
    const float* wq = wsqC + kbase + col;

    for (int g = 0; g < 16; g++) {
#pragma unroll
        for (int t = 0; t < 4; t++) {
            const int4* p = (const int4*)(wb + (size_t)(g * 4 + t) * 2048);
            union { int4 q; bf16x8 v; } bh0, bh1;
            bh0.q = p[lane];
            bh1.q = p[64 + lane];
            float wsqv = wq[g * 64 + t * 16];
            // key low-10 bits = (tile_id<<4) | col  => code - kbase
            unsigned sxor = (1023u ^ (unsigned)((g * 4 + t) << 4)) ^ (unsigned)col;
#pragma unroll
            for (int rt = 0; rt < 2; rt++) {
                f32x4 acc = {0.f, 0.f, 0.f, 0.f};
                acc = __builtin_amdgcn_mfma_f32_16x16x32_bf16(ah[rt][0], bh0.v, acc, 0, 0, 0);
                acc = __builtin_amdgcn_mfma_f32_16x16x32_bf16(ah[rt][1], bh1.v, acc, 0, 0, 0);
                acc = __builtin_amdgcn_mfma_f32_16x16x32_bf16(al[rt][0], bh0.v, acc, 0, 0, 0);
                acc = __builtin_amdgcn_mfma_f32_16x16x32_bf16(al[rt][1], bh1.v, acc, 0, 0, 0);
#pragma unroll
                for (int r = 0; r < 4; r++) {
                    float c = fmaf(-2.0f, acc[r], wsqv);            // c' = c + 4 > 0
                    unsigned k = (__float_as_uint(c) | 1023u) ^ sxor;
                    int s = rt * 4 + r;
                    sec_u[s]  = umn(sec_u[s], umx(best_u[s], k));
                    best_u[s] = umn(best_u[s], k);
                }
            }
        }
    }

    // pure-uint butterfly across the 16 columns (id rides in the low 10 bits)
#pragma unroll
    for (int m = 1; m < 16; m <<= 1) {
#pragma unroll
        for (int s = 0; s < 8; s++) {
            unsigned ob = (unsigned)__shfl_xor((int)best_u[s], m, 64);
            unsigned os = (unsigned)__shfl_xor((int)sec_u[s], m, 64);
            sec_u[s]  = umn(umn(sec_u[s], os), umx(best_u[s], ob));
            best_u[s] = umn(best_u[s], ob);
        }
    }
    if (col == 0) {
        int g4 = lane >> 4;
#pragma unroll
        for (int rt = 0; rt < 2; rt++)
#pragma unroll
            for (int r = 0; r < 4; r++) {
                int row = rbase + rt * 16 + g4 * 4 + r;
                int s = rt * 4 + r;
                unsigned bk = best_u[s], sk = sec_u[s];
                int code = kbase + (int)(bk & 1023u);
                float cb = __uint_as_float(bk | 1023u) - C_OFF;
                float cs = __uint_as_float(sk | 1023u) - C_OFF;
                bestk[(size_t)blockIdx.y * N_ROWS + row] =
                    ((unsigned long long)f2u_ord(cb) << 32) | (unsigned)code;
                secd [(size_t)blockIdx.y * N_ROWS + row] = cs;
            }
    }
}

// ---------------- kernel 2: merge chunks, global flag list ------------------
__global__ __launch_bounds__(256) void vq_merge(const unsigned long long* __restrict__ bestk,
                                                const float* __restrict__ secd,
                                                int* __restrict__ final_idx,
                                                int* __restrict__ rrows,
                                                int* __restrict__ rcount) {
    int row = blockIdx.x * 256 + threadIdx.x;

    unsigned long long ks[KSPLIT];
#pragma unroll
    for (int c = 0; c < KSPLIT; c++) ks[c] = bestk[(size_t)c * N_ROWS + row];

    unsigned long long k1 = ks[0];
#pragma unroll
    for (int c = 1; c < KSPLIT; c++) k1 = (ks[c] < k1) ? ks[c] : k1;

    float d1 = u2f_ord((unsigned)(k1 >> 32));
    float d2 = 3.402823466e+38f;
#pragma unroll
    for (int c = 0; c < KSPLIT; c++) {
        if (ks[c] != k1) {
            float bd = u2f_ord((unsigned)(ks[c] >> 32));
            if (bd < d2) d2 = bd;
        }
        float sd = secd[(size_t)c * N_ROWS + row];
        if (sd < d2) d2 = sd;
    }

    final_idx[row] = (int)(k1 & 0xffffffffull);
    if (d2 - d1 < MARGIN) {
        int slot = atomicAdd(rcount, 1);
        rrows[slot] = row;
    }
}

// ---------------- kernel 3: load-balanced np-exact rescan, 4 rows/batch -----
__global__ __launch_bounds__(256) void vq_rescan(const float* __restrict__ inp,
                                                 const float* __restrict__ weight,
                                                 const float* __restrict__ wsq,
                                                 const int* __restrict__ rrows,
                                                 const int* __restrict__ rcount,
                                                 int* __restrict__ final_idx) {
    __shared__ float xs[4][64];
    __shared__ float x2s[4];
    __shared__ int   sRow[4];
    __shared__ float sRd[4][4];   // [wave][row]
    __shared__ int   sRi[4][4];

    int tid = threadIdx.x;
    int wave = tid >> 6, lane = tid & 63;
    int cnt = *rcount;
    if (cnt > N_ROWS) cnt = N_ROWS;

    for (int b = blockIdx.x * 4; b < cnt; b += gridDim.x * 4) {
        int nb = cnt - b; if (nb > 4) nb = 4;
        if (wave < nb) {
            int row = rrows[b + wave];
            if (lane == 0) sRow[wave] = row;
            xs[wave][lane] = inp[(size_t)row * DIM + lane];
        } else {
            xs[wave][lane] = 0.f;   // keep unused-row math finite
        }
        __syncthreads();
        if (tid < 4) x2s[tid] = np_pairwise_sq64(xs[tid]);
        __syncthreads();
        float x20 = x2s[0], x21 = x2s[1], x22 = x2s[2], x23 = x2s[3];

        float bd0 = 3.402823466e+38f, bd1 = bd0, bd2 = bd0, bd3 = bd0;
        int bi0 = 0x7fffffff, bi1 = bi0, bi2 = bi0, bi3 = bi0;

        for (int code = tid; code < K_CODES; code += 256) {
            const float4* wp4 = (const float4*)(weight + (size_t)code * DIM);
            float s0 = 0.f, s1 = 0.f, s2 = 0.f, s3 = 0.f;
#pragma unroll
            for (int i = 0; i < 16; i++) {
                float4 w = wp4[i];
                const float* a0 = &xs[0][4 * i];
                const float* a1 = &xs[1][4 * i];
                const float* a2 = &xs[2][4 * i];
                const float* a3 = &xs[3][4 * i];
                s0 = __builtin_fmaf(a0[0], w.x, s0);
                s1 = __builtin_fmaf(a1[0], w.x, s1);
                s2 = __builtin_fmaf(a2[0], w.x, s2);
                s3 = __builtin_fmaf(a3[0], w.x, s3);
                s0 = __builtin_fmaf(a0[1], w.y, s0);
                s1 = __builtin_fmaf(a1[1], w.y, s1);
                s2 = __builtin_fmaf(a2[1], w.y, s2);
                s3 = __builtin_fmaf(a3[1], w.y, s3);
                s0 = __builtin_fmaf(a0[2], w.z, s0);
                s1 = __builtin_fmaf(a1[2], w.z, s1);
                s2 = __builtin_fmaf(a2[2], w.z, s2);
                s3 = __builtin_fmaf(a3[2], w.z, s3);
                s0 = __builtin_fmaf(a0[3], w.w, s0);
                s1 = __builtin_fmaf(a1[3], w.w, s1);
                s2 = __builtin_fmaf(a2[3], w.w, s2);
                s3 = __builtin_fmaf(a3[3], w.w, s3);
            }
            float wqv = wsq[code];
            float d0 = __fsub_rn(__fadd_rn(x20, wqv), __fmul_rn(2.0f, s0));
            float d1 = __fsub_rn(__fadd_rn(x21, wqv), __fmul_rn(2.0f, s1));
            float d2 = __fsub_rn(__fadd_rn(x22, wqv), __fmul_rn(2.0f, s2));
            float d3 = __fsub_rn(__fadd_rn(x23, wqv), __fmul_rn(2.0f, s3));
            if (d0 < bd0) { bd0 = d0; bi0 = code; }
            if (d1 < bd1) { bd1 = d1; bi1 = code; }
            if (d2 < bd2) { bd2 = d2; bi2 = code; }
            if (d3 < bd3) { bd3 = d3; bi3 = code; }
        }

        // wave-level lexicographic min-reduce per row
#pragma unroll
        for (int o = 32; o > 0; o >>= 1) {
            float od; int oi;
            od = __shfl_down(bd0, o, 64); oi = __shfl_down(bi0, o, 64);
            if (od < bd0 || (od == bd0 && oi < bi0)) { bd0 = od; bi0 = oi; }
            od = __shfl_down(bd1, o, 64); oi = __shfl_down(bi1, o, 64);
            if (od < bd1 || (od == bd1 && oi < bi1)) { bd1 = od; bi1 = oi; }
            od = __shfl_down(bd2, o, 64); oi = __shfl_down(bi2, o, 64);
            if (od < bd2 || (od == bd2 && oi < bi2)) { bd2 = od; bi2 = oi; }
            od = __shfl_down(bd3, o, 64); oi = __shfl_down(bi3, o, 64);
            if (od < bd3 || (od == bd3 && oi < bi3)) { bd3 = od; bi3 = oi; }
        }
        if (lane == 0) {
            sRd[wave][0] = bd0; sRi[wave][0] = bi0;
            sRd[wave][1] = bd1; sRi[wave][1] = bi1;
            sRd[wave][2] = bd2; sRi[wave][2] = bi2;
            sRd[wave][3] = bd3; sRi[wave][3] = bi3;
        }
        __syncthreads();
        if (tid < nb) {
            float best = sRd[0][tid]; int bi = sRi[0][tid];
#pragma unroll
            for (int w = 1; w < 4; w++) {
                float d = sRd[w][tid]; int i = sRi[w][tid];
                if (d < best || (d == best && i < bi)) { best = d; bi = i; }
            }
            final_idx[sRow[tid]] = bi;
        }
        __syncthreads();
    }
}

// ---------------- kernel 4: gather + STE + loss + index write ----------------
__global__ __launch_bounds__(256) void vq_epilogue(const float* __restrict__ inp,
                                                   const float* __restrict__ weight,
                                                   const int* __restrict__ final_idx,
                                                   float* __restrict__ out) {
    int gid = blockIdx.x * 256 + threadIdx.x;
    int row = gid >> 4;
    int sub = gid & 15;

    int idx = final_idx[row];

    float4 x = ((const float4*)inp)[gid];
    float4 w = ((const float4*)weight)[idx * 16 + sub];

    float4 q;
    q.x = x.x + (w.x - x.x);
    q.y = x.y + (w.y - x.y);
    q.z = x.z + (w.z - x.z);
    q.w = x.w + (w.w - x.w);
    ((float4*)(out + OUT_Q))[gid] = q;

    if (sub == 0) out[OUT_IDX + row] = (float)idx;

    float dx = w.x - x.x, dy = w.y - x.y, dz = w.z - x.z, dw = w.w - x.w;
    float lp = dx * dx + dy * dy + dz * dz + dw * dw;

#pragma unroll
    for (int o = 32; o > 0; o >>= 1) lp += __shfl_down(lp, o, 64);

    __shared__ float red[4];
    int wid = threadIdx.x >> 6;
    int lane = threadIdx.x & 63;
    if (lane == 0) red[wid] = lp;
    __syncthreads();
    if (threadIdx.x == 0) {
        float bs = red[0] + red[1] + red[2] + red[3];
        atomicAdd(out + OUT_LOSS, bs * (0.25f / 2097152.f));
    }
}

extern "C" void kernel_launch(void* const* d_in, const int* in_sizes, int n_in,
                              void* d_out, int out_size, void* d_ws, size_t ws_size,
                              hipStream_t stream) {
    const float* inp = (const float*)d_in[0];
    const float* weight = (const float*)d_in[1];
    float* out = (float*)d_out;

    char* ws = (char*)d_ws;
    unsigned long long* bestk = (unsigned long long*)ws;              // 2 MB
    float* secd      = (float*)(ws + (size_t)KSPLIT * N_ROWS * 8);    // 1 MB
    char*  p         = ws + (size_t)KSPLIT * N_ROWS * 12;
    int*   final_idx = (int*)p;                                       // 128 KB
    int*   rrows     = (int*)(p + (size_t)N_ROWS * 4);                // 128 KB
    int*   rcount    = (int*)(p + (size_t)N_ROWS * 8);                // 256 B
    float* wsq       = (float*)(p + (size_t)N_ROWS * 8 + 256);        // 32 KB
    float* wsqC      = (float*)(p + (size_t)N_ROWS * 8 + 256 + 32768);// 32 KB
    int4*  packedW   = (int4*)(p + (size_t)N_ROWS * 8 + 256 + 65536); // 1 MB

    vq_prep<<<128, 256, 0, stream>>>(weight, wsq, wsqC, packedW, rcount, out);
    vq_argmin<<<dim3(N_ROWS / 128, KSPLIT), 256, 0, stream>>>(inp, packedW, wsqC, bestk, secd);
    vq_merge<<<N_ROWS / 256, 256, 0, stream>>>(bestk, secd, final_idx, rrows, rcount);
    vq_rescan<<<512, 256, 0, stream>>>(inp, weight, wsq, rrows, rcount, final_idx);
    vq_epilogue<<<(N_ROWS * DIM / 4) / 256, 256, 0, stream>>>(inp, weight, final_idx, out);
}